// Round 1
// baseline (895.537 us; speedup 1.0000x reference)
//
#include <hip/hip_runtime.h>
#include <hip/hip_bf16.h>

// Problem constants (match reference setup_inputs).
#define NN    100000
#define EE    1600000
#define DD    9
#define INF   128
#define OUTF  64
#define DOUT  (DD * OUTF)   // 576

typedef __bf16 bf16x8 __attribute__((ext_vector_type(8)));
typedef float  f32x4  __attribute__((ext_vector_type(4)));

__device__ __forceinline__ unsigned short f32_to_bf16_rne(float f) {
    unsigned int u = __float_as_uint(f);
    unsigned int r = u + 0x7FFFu + ((u >> 16) & 1u);
    return (unsigned short)(r >> 16);
}

__device__ __forceinline__ float bf16_to_f32(unsigned short h) {
    return __uint_as_float(((unsigned int)h) << 16);
}

// ---- f32 -> bf16 bulk convert (float4 in, ushort4 out) ----
__global__ __launch_bounds__(256) void cvt_bf16_kernel(
    const float* __restrict__ in, unsigned short* __restrict__ out, int n4)
{
    int i = blockIdx.x * 256 + threadIdx.x;
    if (i < n4) {
        float4 v = reinterpret_cast<const float4*>(in)[i];
        ushort4 o;
        o.x = f32_to_bf16_rne(v.x);
        o.y = f32_to_bf16_rne(v.y);
        o.z = f32_to_bf16_rne(v.z);
        o.w = f32_to_bf16_rne(v.w);
        reinterpret_cast<ushort4*>(out)[i] = o;
    }
}

// ---- Wh[n][d][o] = (feature[n] . W[d][o]) * norm[n], bf16 out ----
// grid.x = ceil(N/64), grid.y = D; block = 256 (4 waves, each wave: 16 nodes x 64 outs)
__global__ __launch_bounds__(256) void gemm_wh_kernel(
    const unsigned short* __restrict__ featb,   // [N][128] bf16
    const unsigned short* __restrict__ Wb,      // [D][64][128] bf16
    const float* __restrict__ norm,             // [N]
    unsigned short* __restrict__ Wh)            // [N][D*64] bf16
{
    const int d    = blockIdx.y;
    const int wave = threadIdx.x >> 6;
    const int lane = threadIdx.x & 63;
    const int quad = lane >> 4;
    const int m16  = lane & 15;
    const int node_base = blockIdx.x * 64 + wave * 16;

    // A fragments: A[m=lane&15][k=quad*8+j], 4 k-steps of 32
    bf16x8 afrag[4];
    const int nodeA = node_base + m16;
    if (nodeA < NN) {
        const bf16x8* ap = reinterpret_cast<const bf16x8*>(featb + (size_t)nodeA * INF + quad * 8);
        #pragma unroll
        for (int k = 0; k < 4; ++k) afrag[k] = ap[k * 4];  // +k*32 elements
    } else {
        #pragma unroll
        for (int k = 0; k < 4; ++k) afrag[k] = bf16x8{};
    }

    f32x4 acc[4] = {f32x4{0,0,0,0}, f32x4{0,0,0,0}, f32x4{0,0,0,0}, f32x4{0,0,0,0}};

    // B[k][n] = W[d][n][k]; lane holds n=lane&15 (+f*16), k=quad*8+j — contiguous 16B in W row
    const unsigned short* wbase = Wb + (size_t)d * OUTF * INF;
    #pragma unroll
    for (int k = 0; k < 4; ++k) {
        #pragma unroll
        for (int f = 0; f < 4; ++f) {
            const bf16x8 bfrag = *reinterpret_cast<const bf16x8*>(
                wbase + (size_t)(f * 16 + m16) * INF + k * 32 + quad * 8);
            acc[f] = __builtin_amdgcn_mfma_f32_16x16x32_bf16(afrag[k], bfrag, acc[f], 0, 0, 0);
        }
    }

    // C/D layout: col = lane&15, row = quad*4 + r
    #pragma unroll
    for (int r = 0; r < 4; ++r) {
        const int node = node_base + quad * 4 + r;
        if (node < NN) {
            const float nm = norm[node];
            unsigned short* o = Wh + (size_t)node * DOUT + d * OUTF + m16;
            #pragma unroll
            for (int f = 0; f < 4; ++f) {
                o[f * 16] = f32_to_bf16_rne(acc[f][r] * nm);
            }
        }
    }
}

// ---- edge scatter: one wave per edge, lane o atomically adds Wh[src][div][o] ----
__global__ __launch_bounds__(256) void scatter_kernel(
    const unsigned short* __restrict__ Wh,
    const int* __restrict__ src, const int* __restrict__ dst,
    const int* __restrict__ ediv, float* __restrict__ out, int E)
{
    int t = blockIdx.x * 256 + threadIdx.x;
    int e = t >> 6;
    int lane = t & 63;
    if (e < E) {
        int s  = src[e];
        int dd = dst[e];
        int dv = ediv[e];
        float v = bf16_to_f32(Wh[(size_t)s * DOUT + dv * OUTF + lane]);
        unsafeAtomicAdd(out + ((size_t)dd * DOUT + dv * OUTF + lane), v);
    }
}

// ---- out = relu(out * norm[dst]) in place, float4 ----
__global__ __launch_bounds__(256) void relu_scale_kernel(
    float* __restrict__ out, const float* __restrict__ norm, int n4)
{
    int i = blockIdx.x * 256 + threadIdx.x;
    if (i < n4) {
        int n = i / (DOUT / 4);   // 144 float4s per node row
        float nm = norm[n];
        float4 v = reinterpret_cast<float4*>(out)[i];
        v.x = fmaxf(v.x * nm, 0.0f);
        v.y = fmaxf(v.y * nm, 0.0f);
        v.z = fmaxf(v.z * nm, 0.0f);
        v.w = fmaxf(v.w * nm, 0.0f);
        reinterpret_cast<float4*>(out)[i] = v;
    }
}

extern "C" void kernel_launch(void* const* d_in, const int* in_sizes, int n_in,
                              void* d_out, int out_size, void* d_ws, size_t ws_size,
                              hipStream_t stream) {
    const float* feature = (const float*)d_in[0];   // [N,128]
    const float* norm    = (const float*)d_in[1];   // [N,1]
    const float* W       = (const float*)d_in[2];   // [D,64,128]
    const int*   src     = (const int*)d_in[3];     // [E]
    const int*   dst     = (const int*)d_in[4];     // [E]
    const int*   ediv    = (const int*)d_in[5];     // [E]
    float* out = (float*)d_out;                     // [N, 576]

    // Workspace layout (all 16B aligned):
    //   Wh    bf16 [N][576]   = 115,200,000 B
    //   featb bf16 [N][128]   =  25,600,000 B
    //   Wb    bf16 [D][64][128] =  147,456 B
    unsigned short* Wh    = (unsigned short*)d_ws;
    unsigned short* featb = Wh + (size_t)NN * DOUT;
    unsigned short* Wb    = featb + (size_t)NN * INF;

    // zero output (scatter target) — graph-capturable stream memset
    hipMemsetAsync(d_out, 0, (size_t)NN * DOUT * sizeof(float), stream);

    // convert feature and W to bf16
    const int nf4 = NN * INF / 4;        // 3,200,000
    cvt_bf16_kernel<<<(nf4 + 255) / 256, 256, 0, stream>>>(feature, featb, nf4);
    const int nw4 = DD * OUTF * INF / 4; // 18,432
    cvt_bf16_kernel<<<(nw4 + 255) / 256, 256, 0, stream>>>(W, Wb, nw4);

    // per-division projection GEMM (MFMA bf16), fused src-norm scale
    dim3 g1((NN + 63) / 64, DD);
    gemm_wh_kernel<<<g1, 256, 0, stream>>>(featb, Wb, norm, Wh);

    // edge scatter-add
    const int nthreads = EE * 64;
    scatter_kernel<<<nthreads / 256, 256, 0, stream>>>(Wh, src, dst, ediv, out, EE);

    // dst-norm scale + relu
    const int n4 = NN * DOUT / 4;        // 14,400,000
    relu_scale_kernel<<<(n4 + 255) / 256, 256, 0, stream>>>(out, norm, n4);
}

// Round 2
// 807.917 us; speedup vs baseline: 1.1085x; 1.1085x over previous
//
#include <hip/hip_runtime.h>
#include <hip/hip_bf16.h>

// Problem constants (match reference setup_inputs).
#define NN    100000
#define EE    1600000
#define DD    9
#define INF   128
#define OUTF  64
#define DOUT  (DD * OUTF)   // 576
#define NBINS (NN * DD)     // 900000 (dst,div) bins

typedef __bf16 bf16x8 __attribute__((ext_vector_type(8)));
typedef float  f32x4  __attribute__((ext_vector_type(4)));
typedef unsigned short us4 __attribute__((ext_vector_type(4)));

__device__ __forceinline__ unsigned short f32_to_bf16_rne(float f) {
    unsigned int u = __float_as_uint(f);
    unsigned int r = u + 0x7FFFu + ((u >> 16) & 1u);
    return (unsigned short)(r >> 16);
}

__device__ __forceinline__ float bf16_to_f32(unsigned short h) {
    return __uint_as_float(((unsigned int)h) << 16);
}

// ---- f32 -> bf16 bulk convert (float4 in, ushort4 out) ----
__global__ __launch_bounds__(256) void cvt_bf16_kernel(
    const float* __restrict__ in, unsigned short* __restrict__ out, int n4)
{
    int i = blockIdx.x * 256 + threadIdx.x;
    if (i < n4) {
        float4 v = reinterpret_cast<const float4*>(in)[i];
        ushort4 o;
        o.x = f32_to_bf16_rne(v.x);
        o.y = f32_to_bf16_rne(v.y);
        o.z = f32_to_bf16_rne(v.z);
        o.w = f32_to_bf16_rne(v.w);
        reinterpret_cast<ushort4*>(out)[i] = o;
    }
}

// ---- Wh[n][d][o] = (feature[n] . W[d][o]) * norm[n], bf16 out ----
// A = W rows (m=channel), B = feature rows (n=node). C: col=lane&15 -> node,
// row=quad*4+r -> channel. Lane then owns 4 CONSECUTIVE channels per fragment
// -> single 8B ushort4 store per fragment (coalesced in 32B chunks per node).
// grid = (ceil(N/64), D); block = 256 (4 waves, each wave: 16 nodes x 64 ch)
__global__ __launch_bounds__(256) void gemm_wh_kernel(
    const unsigned short* __restrict__ featb,   // [N][128] bf16
    const unsigned short* __restrict__ Wb,      // [D][64][128] bf16
    const float* __restrict__ norm,             // [N]
    unsigned short* __restrict__ Wh)            // [N][D*64] bf16
{
    const int d    = blockIdx.y;
    const int wave = threadIdx.x >> 6;
    const int lane = threadIdx.x & 63;
    const int quad = lane >> 4;
    const int m16  = lane & 15;
    const int node = blockIdx.x * 64 + wave * 16 + m16;

    // B fragments: B[k=quad*8+j][n=lane&15] = feature[node][k], 4 k-steps of 32
    bf16x8 bfrag[4];
    if (node < NN) {
        const bf16x8* bp = reinterpret_cast<const bf16x8*>(featb + (size_t)node * INF + quad * 8);
        #pragma unroll
        for (int k = 0; k < 4; ++k) bfrag[k] = bp[k * 4];  // +k*32 elements
    } else {
        #pragma unroll
        for (int k = 0; k < 4; ++k) bfrag[k] = bf16x8{};
    }

    f32x4 acc[4] = {f32x4{0,0,0,0}, f32x4{0,0,0,0}, f32x4{0,0,0,0}, f32x4{0,0,0,0}};

    // A fragments: A[m=lane&15][k=quad*8+j] = W[d][f*16+m16][k]
    const unsigned short* wbase = Wb + (size_t)d * OUTF * INF;
    #pragma unroll
    for (int k = 0; k < 4; ++k) {
        #pragma unroll
        for (int f = 0; f < 4; ++f) {
            const bf16x8 afrag = *reinterpret_cast<const bf16x8*>(
                wbase + (size_t)(f * 16 + m16) * INF + k * 32 + quad * 8);
            acc[f] = __builtin_amdgcn_mfma_f32_16x16x32_bf16(afrag, bfrag[k], acc[f], 0, 0, 0);
        }
    }

    // C/D: col=lane&15 (node), row=quad*4+r (channel within 16-group f)
    if (node < NN) {
        const float nm = norm[node];
        unsigned short* o = Wh + (size_t)node * DOUT + d * OUTF + quad * 4;
        #pragma unroll
        for (int f = 0; f < 4; ++f) {
            us4 p;
            p[0] = f32_to_bf16_rne(acc[f][0] * nm);
            p[1] = f32_to_bf16_rne(acc[f][1] * nm);
            p[2] = f32_to_bf16_rne(acc[f][2] * nm);
            p[3] = f32_to_bf16_rne(acc[f][3] * nm);
            *reinterpret_cast<us4*>(o + f * 16) = p;
        }
    }
}

// ---- CSR build: histogram over (dst*9+div) bins ----
__global__ __launch_bounds__(256) void hist_kernel(
    const int* __restrict__ dst, const int* __restrict__ ediv,
    int* __restrict__ count)
{
    int e = blockIdx.x * 256 + threadIdx.x;
    if (e < EE) atomicAdd(&count[dst[e] * DD + ediv[e]], 1);
}

// ---- segment allocation: base[g] = exclusive-prefix(count) via block scan +
//      one global cursor atomic per block (order across blocks irrelevant,
//      segments just need to be disjoint). ----
__global__ __launch_bounds__(256) void alloc_kernel(
    const int* __restrict__ count, int* __restrict__ basep,
    int* __restrict__ cur, int* __restrict__ cursor)
{
    __shared__ int wtot[4];
    __shared__ int bbase;
    const int lane = threadIdx.x & 63;
    const int wv   = threadIdx.x >> 6;
    const int g = blockIdx.x * 256 + threadIdx.x;
    const int c = (g < NBINS) ? count[g] : 0;
    // inclusive wave scan
    int s = c;
    #pragma unroll
    for (int o = 1; o < 64; o <<= 1) {
        int t = __shfl_up(s, o);
        if (lane >= o) s += t;
    }
    if (lane == 63) wtot[wv] = s;
    __syncthreads();
    if (threadIdx.x == 0) {
        int t0 = wtot[0], t1 = wtot[1], t2 = wtot[2], t3 = wtot[3];
        bbase = atomicAdd(cursor, t0 + t1 + t2 + t3);
        wtot[0] = 0; wtot[1] = t0; wtot[2] = t0 + t1; wtot[3] = t0 + t1 + t2;
    }
    __syncthreads();
    int base = bbase + wtot[wv] + (s - c);  // exclusive within wave
    if (g < NBINS) { basep[g] = base; cur[g] = base; }
}

// ---- fill: payload[slot] = src, slot allocated via per-bin cursor ----
__global__ __launch_bounds__(256) void fill_kernel(
    const int* __restrict__ src, const int* __restrict__ dst,
    const int* __restrict__ ediv, int* __restrict__ cur,
    int* __restrict__ payload)
{
    int e = blockIdx.x * 256 + threadIdx.x;
    if (e < EE) {
        int g = dst[e] * DD + ediv[e];
        int idx = atomicAdd(&cur[g], 1);
        payload[idx] = src[e];
    }
}

// ---- gather: one wave per (node,div) bin; lane = out channel.
//      acc = sum over bin edges of Wh[src][div][lane]; out = relu(acc*norm). ----
__global__ __launch_bounds__(256) void gather_kernel(
    const unsigned short* __restrict__ Wh, const int* __restrict__ payload,
    const int* __restrict__ basep, const int* __restrict__ count,
    const float* __restrict__ norm, float* __restrict__ out)
{
    const int wv   = threadIdx.x >> 6;
    const int lane = threadIdx.x & 63;
    const int g = blockIdx.x * 4 + wv;
    if (g >= NBINS) return;
    const int b = basep[g];
    const int c = count[g];
    const int n  = g / DD;
    const int dv = g - n * DD;
    float acc = 0.0f;
    int i = 0;
    for (; i + 2 <= c; i += 2) {
        int p0 = payload[b + i];
        int p1 = payload[b + i + 1];
        float v0 = bf16_to_f32(Wh[(size_t)p0 * DOUT + dv * OUTF + lane]);
        float v1 = bf16_to_f32(Wh[(size_t)p1 * DOUT + dv * OUTF + lane]);
        acc += v0 + v1;
    }
    if (i < c) {
        int p = payload[b + i];
        acc += bf16_to_f32(Wh[(size_t)p * DOUT + dv * OUTF + lane]);
    }
    out[(size_t)n * DOUT + dv * OUTF + lane] = fmaxf(acc * norm[n], 0.0f);
}

extern "C" void kernel_launch(void* const* d_in, const int* in_sizes, int n_in,
                              void* d_out, int out_size, void* d_ws, size_t ws_size,
                              hipStream_t stream) {
    const float* feature = (const float*)d_in[0];   // [N,128]
    const float* norm    = (const float*)d_in[1];   // [N,1]
    const float* W       = (const float*)d_in[2];   // [D,64,128]
    const int*   src     = (const int*)d_in[3];     // [E]
    const int*   dst     = (const int*)d_in[4];     // [E]
    const int*   ediv    = (const int*)d_in[5];     // [E]
    float* out = (float*)d_out;                     // [N, 576]

    // Workspace layout (total 140,947,460 B — same footprint as round 1):
    //   Wh    bf16 [N][576]      @ 0          (115,200,000 B)
    //   R2    region              @ 115,200,000 (25,600,000 B):
    //     phase 1 (until gemm done): featb bf16 [N][128]
    //     phase 2 (CSR build, aliases featb — stream is serial):
    //       count[NBINS] @ +0, basep[NBINS] @ +3.6e6, cur[NBINS] @ +7.2e6,
    //       payload[E]   @ +10.8e6, cursor @ +17.2e6
    //   Wb    bf16 [D][64][128]  @ 140,800,000 (147,456 B)
    char* ws = (char*)d_ws;
    unsigned short* Wh    = (unsigned short*)ws;
    char* R2 = ws + 115200000;
    unsigned short* featb = (unsigned short*)R2;
    unsigned short* Wb    = (unsigned short*)(ws + 140800000);
    int* count   = (int*)R2;
    int* basep   = (int*)(R2 + 3600000);
    int* cur     = (int*)(R2 + 7200000);
    int* payload = (int*)(R2 + 10800000);
    int* cursor  = (int*)(R2 + 17200000);

    // 1) convert feature and W to bf16
    const int nf4 = NN * INF / 4;        // 3,200,000
    cvt_bf16_kernel<<<(nf4 + 255) / 256, 256, 0, stream>>>(feature, featb, nf4);
    const int nw4 = DD * OUTF * INF / 4; // 18,432
    cvt_bf16_kernel<<<(nw4 + 255) / 256, 256, 0, stream>>>(W, Wb, nw4);

    // 2) per-division projection (MFMA bf16), fused src-norm scale
    dim3 g1((NN + 63) / 64, DD);
    gemm_wh_kernel<<<g1, 256, 0, stream>>>(featb, Wb, norm, Wh);

    // 3) CSR build over (dst,div) bins — featb is dead now, alias its region
    hipMemsetAsync(count, 0, (size_t)NBINS * sizeof(int), stream);
    hipMemsetAsync(cursor, 0, sizeof(int), stream);
    hist_kernel<<<(EE + 255) / 256, 256, 0, stream>>>(dst, ediv, count);
    alloc_kernel<<<(NBINS + 255) / 256, 256, 0, stream>>>(count, basep, cur, cursor);
    fill_kernel<<<(EE + 255) / 256, 256, 0, stream>>>(src, dst, ediv, cur, payload);

    // 4) gather + fused dst-norm scale + relu (writes every output element)
    gather_kernel<<<(NBINS + 3) / 4, 256, 0, stream>>>(Wh, payload, basep, count, norm, out);
}